// Round 7
// baseline (340.843 us; speedup 1.0000x reference)
//
#include <hip/hip_runtime.h>
#include <hip/hip_bf16.h>
#include <math.h>

#define TOKENS 16384
#define DIM 4096
#define NEXP 64
#define TOPK 8
#define FILTER_R 0.62f
#define LOAD_LR 0.001f
#define EPS_GAP 5e-5f     // fp32 accum err ~6e-7 RMS; 40x margin. ~50 tokens flagged.

#define TM 4              // tokens per wave
#define WAVES 4           // waves per block -> 16 tokens/block, 1024 blocks
#define TB (TM * WAVES)
#define GRP 64            // k-floats per group per row (1 float4/lane covers 4 rows x 64)
#define NG (DIM / GRP)    // 64 groups

// ws: [0,1MB) Wt4; then hist[64], flag_cnt[1], flag_list[16384]
// Wt4: element (k,e) at float idx (k>>2)*256 + e*4 + (k&3); as float4: (k>>2)*64+e.
__global__ void wt_transpose_kernel(const float* __restrict__ W,
                                    float* __restrict__ wt4,
                                    int* __restrict__ hist) {
    int tid = blockIdx.x * blockDim.x + threadIdx.x;
    if (blockIdx.x == 0 && threadIdx.x < NEXP) hist[threadIdx.x] = 0;
    if (blockIdx.x == 0 && threadIdx.x == NEXP) hist[NEXP] = 0;   // flag_cnt
    int e = tid >> 12;
    int k = tid & (DIM - 1);
    wt4[((k >> 2) << 8) + (e << 2) + (k & 3)] = W[tid];
}

__device__ __forceinline__ float rdlane(float v, int l) {
    return __uint_as_float(__builtin_amdgcn_readlane(__float_as_uint(v), l));
}

__global__ __launch_bounds__(256, 4) void router_kernel(
    const float* __restrict__ x,
    const float* __restrict__ b,
    const float* __restrict__ bi,
    const float* __restrict__ rand_u,
    const float4* __restrict__ wt4,
    float* __restrict__ out,          // [0,131072) probs, [131072,262144) indices-as-float
    int* __restrict__ hist_g) {       // hist[64] | flag_cnt | flag_list[...]
    __shared__ int lds_hist[NEXP];

    const int lane = threadIdx.x & 63;
    const int wave = __builtin_amdgcn_readfirstlane(threadIdx.x >> 6);
    if (threadIdx.x < NEXP) lds_hist[threadIdx.x] = 0;
    __syncthreads();

    const int t0 = blockIdx.x * TB + wave * TM;
    const int lrow = lane >> 4;       // token row (0..3) this lane loads
    const int lk4  = lane & 15;       // k4 offset within the group

    float4 a4[TM];
#pragma unroll
    for (int t = 0; t < TM; ++t) a4[t] = make_float4(0.f, 0.f, 0.f, 0.f);

    // per-lane vector loads (4 x 256B coalesced segments / instr), reg double-buffer
    const float* xbase = x + (size_t)(t0 + lrow) * DIM + lk4 * 4;
    float4 cur = *(const float4*)xbase;

    for (int g = 0; g < NG; ++g) {
        const int gn = (g + 1) & (NG - 1);          // last iter re-reads g0 (discarded)
        float4 nxt = *(const float4*)(xbase + gn * GRP);
        const float4* wrow = wt4 + (size_t)g * 16 * 64 + lane;
#pragma unroll
        for (int j = 0; j < 16; ++j) {
            float4 wv = wrow[j * 64];               // per-lane, L1/L2-resident
#pragma unroll
            for (int t = 0; t < TM; ++t) {
                const int sl = t * 16 + j;          // compile-time lane
                a4[t].x = fmaf(rdlane(cur.x, sl), wv.x, a4[t].x);
                a4[t].y = fmaf(rdlane(cur.y, sl), wv.y, a4[t].y);
                a4[t].z = fmaf(rdlane(cur.z, sl), wv.z, a4[t].z);
                a4[t].w = fmaf(rdlane(cur.w, sl), wv.w, a4[t].w);
            }
        }
        cur = nxt;
    }

    const float b_lane  = b[lane];
    const float bi_lane = bi[lane];
    int* flag_cnt  = hist_g + NEXP;
    int* flag_list = hist_g + NEXP + 1;

    for (int t = 0; t < TM; ++t) {
        const float vub = ((a4[t].x + a4[t].y) + (a4[t].z + a4[t].w)) + b_lane;
        float cur_l = vub + bi_lane;

        float selv  = -INFINITY;              // lane j (0..8): biased value of j-th pick
        int   selidx = 0;

#pragma unroll
        for (int j = 0; j <= TOPK; ++j) {     // top-9 so the 8/9 boundary is checked
            float bv = cur_l;
            int   bidx = lane;
#pragma unroll
            for (int s = 1; s < 64; s <<= 1) {
                float ov = __shfl_xor(bv, s, 64);
                int   oi = __shfl_xor(bidx, s, 64);
                bool take = (ov > bv) || (ov == bv && oi < bidx);
                if (take) { bv = ov; bidx = oi; }
            }
            if (lane == j) { selv = bv; selidx = bidx; }
            if (lane == bidx) cur_l = -INFINITY;
        }

        const int tt = t0 + t;
        float nxtv = __shfl_down(selv, 1, 64);
        bool  bad  = (lane < TOPK) && (selv - nxtv < EPS_GAP);
        if (__any(bad)) {
            // defer: exact recompute runs in the parallel fallback kernel
            if (lane == 0) {
                int p = atomicAdd(flag_cnt, 1);
                if (p < TOKENS) flag_list[p] = tt;
            }
        } else {
            float out_logit = __shfl(vub, selidx, 64);
            float sv = (lane < TOPK) ? out_logit : -INFINITY;
            float m = sv;
            m = fmaxf(m, __shfl_xor(m, 1, 64));
            m = fmaxf(m, __shfl_xor(m, 2, 64));
            m = fmaxf(m, __shfl_xor(m, 4, 64));
            float e = (lane < TOPK) ? expf(sv - m) : 0.f;
            float ssum = e;
            ssum += __shfl_xor(ssum, 1, 64);
            ssum += __shfl_xor(ssum, 2, 64);
            ssum += __shfl_xor(ssum, 4, 64);
            if (lane < TOPK) {
                float p = e / ssum;
                float r = rand_u[tt * TOPK + lane];
                out[tt * TOPK + lane] = (r > FILTER_R) ? p : 0.f;
                out[TOKENS * TOPK + tt * TOPK + lane] = (float)selidx;
                atomicAdd(&lds_hist[selidx], 1);
            }
        }
    }

    __syncthreads();
    if (threadIdx.x < NEXP) atomicAdd(&hist_g[threadIdx.x], lds_hist[threadIdx.x]);
}

// one wave per flagged token, all tokens in parallel; exact f64 logits
__global__ __launch_bounds__(256) void fallback_kernel(
    const float* __restrict__ x,
    const float* __restrict__ b,
    const float* __restrict__ bi,
    const float* __restrict__ rand_u,
    const float4* __restrict__ wt4,
    float* __restrict__ out,
    int* __restrict__ hist_g) {
    const int lane = threadIdx.x & 63;
    const int wid  = (blockIdx.x * blockDim.x + threadIdx.x) >> 6;
    const int nw   = (gridDim.x * blockDim.x) >> 6;
    const int* flag_cnt  = hist_g + NEXP;
    const int* flag_list = hist_g + NEXP + 1;
    int n = *flag_cnt; if (n > TOKENS) n = TOKENS;

    for (int i = wid; i < n; i += nw) {
        const int tt = flag_list[i];
        const float4* xrow = (const float4*)(x + (size_t)tt * DIM);
        double d0 = 0.0, d1 = 0.0;
#pragma unroll 8
        for (int k4 = 0; k4 < DIM / 4; ++k4) {
            float4 wv = wt4[k4 * 64 + lane];
            float4 xv = xrow[k4];
            d0 = fma((double)xv.x, (double)wv.x, d0);
            d1 = fma((double)xv.y, (double)wv.y, d1);
            d0 = fma((double)xv.z, (double)wv.z, d0);
            d1 = fma((double)xv.w, (double)wv.w, d1);
        }
        const double dvub = (d0 + d1) + (double)b[lane];
        double dcur = dvub + (double)bi[lane];
        float out_logit = -INFINITY;
        int   out_idx   = 0;
#pragma unroll
        for (int j = 0; j < TOPK; ++j) {
            double bv = dcur;
            int    bidx = lane;
#pragma unroll
            for (int s = 1; s < 64; s <<= 1) {
                double ov = __shfl_xor(bv, s, 64);
                int    oi = __shfl_xor(bidx, s, 64);
                bool take = (ov > bv) || (ov == bv && oi < bidx);
                if (take) { bv = ov; bidx = oi; }
            }
            float wub = (float)__shfl(dvub, bidx, 64);
            if (lane == j) { out_logit = wub; out_idx = bidx; }
            if (lane == bidx) dcur = -(double)INFINITY;
        }
        float sv = (lane < TOPK) ? out_logit : -INFINITY;
        float m = sv;
        m = fmaxf(m, __shfl_xor(m, 1, 64));
        m = fmaxf(m, __shfl_xor(m, 2, 64));
        m = fmaxf(m, __shfl_xor(m, 4, 64));
        float e = (lane < TOPK) ? expf(sv - m) : 0.f;
        float ssum = e;
        ssum += __shfl_xor(ssum, 1, 64);
        ssum += __shfl_xor(ssum, 2, 64);
        ssum += __shfl_xor(ssum, 4, 64);
        if (lane < TOPK) {
            float p = e / ssum;
            float r = rand_u[tt * TOPK + lane];
            out[tt * TOPK + lane] = (r > FILTER_R) ? p : 0.f;
            out[TOKENS * TOPK + tt * TOPK + lane] = (float)out_idx;
            atomicAdd(&hist_g[out_idx], 1);
        }
    }
}

__global__ void bias_update_kernel(const float* __restrict__ bi,
                                   const int* __restrict__ hist,
                                   float* __restrict__ out_bi) {
    int e = threadIdx.x;
    float c_avg = (float)TOKENS / (float)NEXP;     // 256
    float e_i = c_avg - (float)hist[e];
    float s = (e_i > 0.f) ? 1.f : ((e_i < 0.f) ? -1.f : 0.f);
    out_bi[e] = bi[e] + LOAD_LR * s;
}

extern "C" void kernel_launch(void* const* d_in, const int* in_sizes, int n_in,
                              void* d_out, int out_size, void* d_ws, size_t ws_size,
                              hipStream_t stream) {
    const float* x      = (const float*)d_in[0];
    const float* W      = (const float*)d_in[1];
    const float* b      = (const float*)d_in[2];
    const float* bi     = (const float*)d_in[3];
    const float* rand_u = (const float*)d_in[4];

    float* out  = (float*)d_out;
    float* wt4  = (float*)d_ws;
    int*   hist = (int*)((char*)d_ws + (size_t)DIM * NEXP * sizeof(float));

    // 1) transpose W; zero hist + flag counter
    wt_transpose_kernel<<<(DIM * NEXP) / 256, 256, 0, stream>>>(W, wt4, hist);

    // 2) fused logits + top-k + softmax; near-ties appended to flag list
    router_kernel<<<TOKENS / TB, 256, 0, stream>>>(
        x, b, bi, rand_u, (const float4*)wt4, out, hist);

    // 3) exact f64 redo for flagged tokens, one wave each, in parallel
    fallback_kernel<<<64, 256, 0, stream>>>(
        x, b, bi, rand_u, (const float4*)wt4, out, hist);

    // 4) load-balance bias update -> out[262144..262208)
    bias_update_kernel<<<1, NEXP, 0, stream>>>(bi, hist, out + 2 * TOKENS * TOPK);
}

// Round 8
// 164.408 us; speedup vs baseline: 2.0732x; 2.0732x over previous
//
#include <hip/hip_runtime.h>
#include <hip/hip_bf16.h>
#include <math.h>

#define TOKENS 16384
#define DIM 4096
#define NEXP 64
#define TOPK 8
#define FILTER_R 0.62f
#define LOAD_LR 0.001f
#define EPS_GAP 1e-4f      // bf16x3 logit err ~1e-6 RMS -> 100x margin; ~100 tokens flagged

typedef __attribute__((ext_vector_type(8))) short bf16x8;   // 8 bf16 in 4 VGPRs
typedef __attribute__((ext_vector_type(4))) float f32x4;

#define NSTEP 128                      // K-steps of 32
#define BFRAG_ELEMS (NSTEP * 4 * 64 * 8)   // 262144 ushorts = 512KB per array

// ws: Bhi[512KB] | Blo[512KB] | hist[64] | flag_cnt | flag_list[16384]

__device__ __forceinline__ unsigned bf16_hi_bits(unsigned u) {
    // RTNE bf16, result as fp32 bit pattern (low 16 cleared)
    return (u + 0x7fffu + ((u >> 16) & 1u)) & 0xffff0000u;
}

// Pack W[E][K] into MFMA B-fragment order, split hi/lo bf16.
// Element Wt[k][n] (k-major): s=k>>5, lane=((k&31)>>3)<<4 | (n&15), e=k&7, f=n>>4
// -> idx = (((s*4+f)*64+lane)*8+e
__global__ void pack_kernel(const float* __restrict__ W,
                            unsigned short* __restrict__ Bhi,
                            unsigned short* __restrict__ Blo,
                            int* __restrict__ hist) {
    int tid = blockIdx.x * blockDim.x + threadIdx.x;   // 0 .. DIM*NEXP-1
    if (blockIdx.x == 0 && threadIdx.x <= NEXP) hist[threadIdx.x] = 0;  // hist + flag_cnt
    int n = tid >> 12;            // expert
    int k = tid & (DIM - 1);
    float w = W[tid];
    unsigned u = __float_as_uint(w);
    unsigned hr = bf16_hi_bits(u);
    float lo = w - __uint_as_float(hr);
    unsigned lr = bf16_hi_bits(__float_as_uint(lo));
    int s = k >> 5, kr = k & 31;
    int lane = ((kr >> 3) << 4) | (n & 15);
    int e = kr & 7, f = n >> 4;
    size_t idx = ((((size_t)s * 4 + f) * 64 + lane) << 3) + e;
    Bhi[idx] = (unsigned short)(hr >> 16);
    Blo[idx] = (unsigned short)(lr >> 16);
}

// ---- router: 1024 blocks x 128 thr (2 waves); wave=K-half; 16 tokens/block --
#define LOADAB(S, A0, A1, H0,H1,H2,H3, L0,L1,L2,L3) {            \
    A0 = *(const float4*)(xrow + (size_t)(S) * 32);              \
    A1 = *(const float4*)(xrow + (size_t)(S) * 32 + 4);          \
    const int bb_ = (S) * 256 + lane;                            \
    H0 = Bh4[bb_];       H1 = Bh4[bb_ + 64];                     \
    H2 = Bh4[bb_ + 128]; H3 = Bh4[bb_ + 192];                    \
    L0 = Bl4[bb_];       L1 = Bl4[bb_ + 64];                     \
    L2 = Bl4[bb_ + 128]; L3 = Bl4[bb_ + 192]; }

#define COMPUTE(A0, A1, H0,H1,H2,H3, L0,L1,L2,L3) {              \
    float fe[8] = {A0.x,A0.y,A0.z,A0.w,A1.x,A1.y,A1.z,A1.w};     \
    short he[8], le[8];                                          \
    _Pragma("unroll")                                            \
    for (int e_ = 0; e_ < 8; ++e_) {                             \
        unsigned u_ = __float_as_uint(fe[e_]);                   \
        unsigned hr_ = bf16_hi_bits(u_);                         \
        he[e_] = (short)(hr_ >> 16);                             \
        float lo_ = fe[e_] - __uint_as_float(hr_);               \
        le[e_] = (short)(bf16_hi_bits(__float_as_uint(lo_)) >> 16); } \
    bf16x8 ah = {he[0],he[1],he[2],he[3],he[4],he[5],he[6],he[7]};    \
    bf16x8 al = {le[0],le[1],le[2],le[3],le[4],le[5],le[6],le[7]};    \
    bf16x8 b_;                                                   \
    b_ = __builtin_bit_cast(bf16x8, H0);                         \
    acc0 = __builtin_amdgcn_mfma_f32_16x16x32_bf16(ah, b_, acc0, 0,0,0); \
    acc0 = __builtin_amdgcn_mfma_f32_16x16x32_bf16(al, b_, acc0, 0,0,0); \
    b_ = __builtin_bit_cast(bf16x8, L0);                         \
    acc0 = __builtin_amdgcn_mfma_f32_16x16x32_bf16(ah, b_, acc0, 0,0,0); \
    b_ = __builtin_bit_cast(bf16x8, H1);                         \
    acc1 = __builtin_amdgcn_mfma_f32_16x16x32_bf16(ah, b_, acc1, 0,0,0); \
    acc1 = __builtin_amdgcn_mfma_f32_16x16x32_bf16(al, b_, acc1, 0,0,0); \
    b_ = __builtin_bit_cast(bf16x8, L1);                         \
    acc1 = __builtin_amdgcn_mfma_f32_16x16x32_bf16(ah, b_, acc1, 0,0,0); \
    b_ = __builtin_bit_cast(bf16x8, H2);                         \
    acc2 = __builtin_amdgcn_mfma_f32_16x16x32_bf16(ah, b_, acc2, 0,0,0); \
    acc2 = __builtin_amdgcn_mfma_f32_16x16x32_bf16(al, b_, acc2, 0,0,0); \
    b_ = __builtin_bit_cast(bf16x8, L2);                         \
    acc2 = __builtin_amdgcn_mfma_f32_16x16x32_bf16(ah, b_, acc2, 0,0,0); \
    b_ = __builtin_bit_cast(bf16x8, H3);                         \
    acc3 = __builtin_amdgcn_mfma_f32_16x16x32_bf16(ah, b_, acc3, 0,0,0); \
    acc3 = __builtin_amdgcn_mfma_f32_16x16x32_bf16(al, b_, acc3, 0,0,0); \
    b_ = __builtin_bit_cast(bf16x8, L3);                         \
    acc3 = __builtin_amdgcn_mfma_f32_16x16x32_bf16(ah, b_, acc3, 0,0,0); }

__global__ __launch_bounds__(128) void router_kernel(
    const float* __restrict__ x,
    const float* __restrict__ b,
    const float* __restrict__ bi,
    const float* __restrict__ rand_u,
    const uint4* __restrict__ Bh4,
    const uint4* __restrict__ Bl4,
    float* __restrict__ out,          // probs | indices-as-float | bi_new
    int* __restrict__ hist_g) {       // hist[64] | flag_cnt | flag_list
    __shared__ float lds_logits[16][NEXP];
    __shared__ int lds_hist[NEXP];

    const int lane = threadIdx.x & 63;
    const int wave = __builtin_amdgcn_readfirstlane(threadIdx.x >> 6);  // K-half
    if (threadIdx.x < NEXP) lds_hist[threadIdx.x] = 0;

    const int t0 = blockIdx.x * 16;
    const int row_a = lane & 15;           // A row (token) / C col (expert) role
    const int kg = lane >> 4;              // A k-group / C row-group
    const float* xrow = x + (size_t)(t0 + row_a) * DIM + kg * 8;
    const int Sb = wave * 64;              // this wave's K-step base

    f32x4 acc0 = {0,0,0,0}, acc1 = {0,0,0,0}, acc2 = {0,0,0,0}, acc3 = {0,0,0,0};

    float4 a0A, a1A, a0B, a1B;
    uint4 h0A,h1A,h2A,h3A, l0A,l1A,l2A,l3A;
    uint4 h0B,h1B,h2B,h3B, l0B,l1B,l2B,l3B;

    LOADAB(Sb, a0A,a1A, h0A,h1A,h2A,h3A, l0A,l1A,l2A,l3A);
    for (int s = 0; s < 64; s += 2) {
        LOADAB(Sb + s + 1, a0B,a1B, h0B,h1B,h2B,h3B, l0B,l1B,l2B,l3B);
        COMPUTE(a0A,a1A, h0A,h1A,h2A,h3A, l0A,l1A,l2A,l3A);
        if (s + 2 < 64)
            LOADAB(Sb + s + 2, a0A,a1A, h0A,h1A,h2A,h3A, l0A,l1A,l2A,l3A);
        COMPUTE(a0B,a1B, h0B,h1B,h2B,h3B, l0B,l1B,l2B,l3B);
    }

    // combine the two K-halves: C layout col=lane&15 (expert), row=(lane>>4)*4+r (token)
    __syncthreads();
    if (wave == 1) {
#pragma unroll
        for (int r = 0; r < 4; ++r) {
            const int tr = kg * 4 + r;
            lds_logits[tr][ 0 + row_a] = acc0[r];
            lds_logits[tr][16 + row_a] = acc1[r];
            lds_logits[tr][32 + row_a] = acc2[r];
            lds_logits[tr][48 + row_a] = acc3[r];
        }
    }
    __syncthreads();
    if (wave == 0) {
#pragma unroll
        for (int r = 0; r < 4; ++r) {
            const int tr = kg * 4 + r;
            lds_logits[tr][ 0 + row_a] += acc0[r];
            lds_logits[tr][16 + row_a] += acc1[r];
            lds_logits[tr][32 + row_a] += acc2[r];
            lds_logits[tr][48 + row_a] += acc3[r];
        }
    }
    __syncthreads();

    const float b_lane  = b[lane];
    const float bi_lane = bi[lane];
    int* flag_cnt  = hist_g + NEXP;
    int* flag_list = hist_g + NEXP + 1;

    for (int t = wave * 8; t < wave * 8 + 8; ++t) {
        const float vub = lds_logits[t][lane] + b_lane;
        float cur_l = vub + bi_lane;

        float selv  = -INFINITY;
        int   selidx = 0;
#pragma unroll
        for (int j = 0; j <= TOPK; ++j) {       // top-9: gap-check 8/9 boundary too
            float bv = cur_l;
            int   bidx = lane;
#pragma unroll
            for (int s = 1; s < 64; s <<= 1) {
                float ov = __shfl_xor(bv, s, 64);
                int   oi = __shfl_xor(bidx, s, 64);
                bool take = (ov > bv) || (ov == bv && oi < bidx);
                if (take) { bv = ov; bidx = oi; }
            }
            if (lane == j) { selv = bv; selidx = bidx; }
            if (lane == bidx) cur_l = -INFINITY;
        }

        const int tt = t0 + t;
        float nxtv = __shfl_down(selv, 1, 64);
        bool  bad  = (lane < TOPK) && (selv - nxtv < EPS_GAP);
        if (__any(bad)) {
            if (lane == 0) {
                int p = atomicAdd(flag_cnt, 1);
                if (p < TOKENS) flag_list[p] = tt;
            }
        } else {
            float out_logit = __shfl(vub, selidx, 64);
            float sv = (lane < TOPK) ? out_logit : -INFINITY;
            float m = sv;
            m = fmaxf(m, __shfl_xor(m, 1, 64));
            m = fmaxf(m, __shfl_xor(m, 2, 64));
            m = fmaxf(m, __shfl_xor(m, 4, 64));
            float e = (lane < TOPK) ? expf(sv - m) : 0.f;
            float ssum = e;
            ssum += __shfl_xor(ssum, 1, 64);
            ssum += __shfl_xor(ssum, 2, 64);
            ssum += __shfl_xor(ssum, 4, 64);
            if (lane < TOPK) {
                float p = e / ssum;
                float r = rand_u[tt * TOPK + lane];
                out[tt * TOPK + lane] = (r > FILTER_R) ? p : 0.f;
                out[TOKENS * TOPK + tt * TOPK + lane] = (float)selidx;
                atomicAdd(&lds_hist[selidx], 1);
            }
        }
    }

    __syncthreads();
    if (threadIdx.x < NEXP) atomicAdd(&hist_g[threadIdx.x], lds_hist[threadIdx.x]);
}

// exact f64 redo: one block per flagged token, 4 waves split K
__global__ __launch_bounds__(256) void fallback_kernel(
    const float* __restrict__ x,
    const float* __restrict__ W,
    const float* __restrict__ b,
    const float* __restrict__ bi,
    const float* __restrict__ rand_u,
    float* __restrict__ out,
    int* __restrict__ hist_g) {
    __shared__ double part[4][64];
    const int lane = threadIdx.x & 63;
    const int wave = threadIdx.x >> 6;
    const int* flag_cnt  = hist_g + NEXP;
    const int* flag_list = hist_g + NEXP + 1;
    int n = *flag_cnt; if (n > TOKENS) n = TOKENS;

    for (int i = blockIdx.x; i < n; i += gridDim.x) {
        const int tt = flag_list[i];
        const float4* xr = (const float4*)(x + (size_t)tt * DIM);
        const float4* wr = (const float4*)(W + (size_t)lane * DIM);
        double d0 = 0.0, d1 = 0.0;
#pragma unroll 4
        for (int k4 = wave * 256; k4 < (wave + 1) * 256; ++k4) {
            float4 xv = xr[k4];
            float4 wv = wr[k4];
            d0 = fma((double)xv.x, (double)wv.x, d0);
            d1 = fma((double)xv.y, (double)wv.y, d1);
            d0 = fma((double)xv.z, (double)wv.z, d0);
            d1 = fma((double)xv.w, (double)wv.w, d1);
        }
        part[wave][lane] = d0 + d1;
        __syncthreads();
        if (wave == 0) {
            const double dvub = ((part[0][lane] + part[1][lane]) +
                                 (part[2][lane] + part[3][lane])) + (double)b[lane];
            double dcur = dvub + (double)bi[lane];
            float out_logit = -INFINITY;
            int   out_idx   = 0;
#pragma unroll
            for (int j = 0; j < TOPK; ++j) {
                double bv = dcur;
                int    bidx = lane;
#pragma unroll
                for (int s = 1; s < 64; s <<= 1) {
                    double ov = __shfl_xor(bv, s, 64);
                    int    oi = __shfl_xor(bidx, s, 64);
                    bool take = (ov > bv) || (ov == bv && oi < bidx);
                    if (take) { bv = ov; bidx = oi; }
                }
                float wub = (float)__shfl(dvub, bidx, 64);
                if (lane == j) { out_logit = wub; out_idx = bidx; }
                if (lane == bidx) dcur = -(double)INFINITY;
            }
            float sv = (lane < TOPK) ? out_logit : -INFINITY;
            float m = sv;
            m = fmaxf(m, __shfl_xor(m, 1, 64));
            m = fmaxf(m, __shfl_xor(m, 2, 64));
            m = fmaxf(m, __shfl_xor(m, 4, 64));
            float e = (lane < TOPK) ? expf(sv - m) : 0.f;
            float ssum = e;
            ssum += __shfl_xor(ssum, 1, 64);
            ssum += __shfl_xor(ssum, 2, 64);
            ssum += __shfl_xor(ssum, 4, 64);
            if (lane < TOPK) {
                float p = e / ssum;
                float r = rand_u[tt * TOPK + lane];
                out[tt * TOPK + lane] = (r > FILTER_R) ? p : 0.f;
                out[TOKENS * TOPK + tt * TOPK + lane] = (float)out_idx;
                atomicAdd(&hist_g[out_idx], 1);
            }
        }
        __syncthreads();
    }
}

__global__ void bias_update_kernel(const float* __restrict__ bi,
                                   const int* __restrict__ hist,
                                   float* __restrict__ out_bi) {
    int e = threadIdx.x;
    float c_avg = (float)TOKENS / (float)NEXP;     // 256
    float e_i = c_avg - (float)hist[e];
    float s = (e_i > 0.f) ? 1.f : ((e_i < 0.f) ? -1.f : 0.f);
    out_bi[e] = bi[e] + LOAD_LR * s;
}

extern "C" void kernel_launch(void* const* d_in, const int* in_sizes, int n_in,
                              void* d_out, int out_size, void* d_ws, size_t ws_size,
                              hipStream_t stream) {
    const float* x      = (const float*)d_in[0];
    const float* W      = (const float*)d_in[1];
    const float* b      = (const float*)d_in[2];
    const float* bi     = (const float*)d_in[3];
    const float* rand_u = (const float*)d_in[4];

    float* out = (float*)d_out;
    unsigned short* Bhi = (unsigned short*)d_ws;
    unsigned short* Blo = Bhi + BFRAG_ELEMS;
    int* hist = (int*)(Blo + BFRAG_ELEMS);

    // 1) split W into bf16 hi/lo, packed in MFMA B-fragment order; zero hist+flag
    pack_kernel<<<(DIM * NEXP) / 256, 256, 0, stream>>>(W, Bhi, Blo, hist);

    // 2) bf16x3 MFMA logits + top-k + softmax; near-ties -> flag list
    router_kernel<<<TOKENS / 16, 128, 0, stream>>>(
        x, b, bi, rand_u, (const uint4*)Bhi, (const uint4*)Blo, out, hist);

    // 3) exact f64 redo for flagged tokens (1 block each, 4-wave K-split)
    fallback_kernel<<<256, 256, 0, stream>>>(x, W, b, bi, rand_u, out, hist);

    // 4) load-balance bias update -> out[262144..262208)
    bias_update_kernel<<<1, NEXP, 0, stream>>>(bi, hist, out + 2 * TOKENS * TOPK);
}

// Round 9
// 145.880 us; speedup vs baseline: 2.3365x; 1.1270x over previous
//
#include <hip/hip_runtime.h>
#include <hip/hip_bf16.h>
#include <math.h>

#define TOKENS 16384
#define DIM 4096
#define NEXP 64
#define TOPK 8
#define FILTER_R 0.62f
#define LOAD_LR 0.001f
#define EPS_GAP 1e-4f      // bf16x3 logit err; empirically flip-free on these inputs

typedef __attribute__((ext_vector_type(8))) short bf16x8;   // 8 bf16 in 4 VGPRs
typedef __attribute__((ext_vector_type(4))) float f32x4;

#define NSTEP 128                      // K-steps of 32
#define KSPLIT 4                       // waves per block, each owns 32 steps
#define STEPS (NSTEP / KSPLIT)
#define BFRAG_ELEMS (NSTEP * 4 * 64 * 8)   // 262144 ushorts = 512KB per array

// ws: Bhi[512KB] | Blo[512KB] | hist[64] | flag_cnt | flag_list[16384]

__device__ __forceinline__ unsigned bf16_hi_bits(unsigned u) {
    // RTNE bf16, result as fp32 bit pattern (low 16 cleared)
    return (u + 0x7fffu + ((u >> 16) & 1u)) & 0xffff0000u;
}

// Pack W[E][K] into MFMA B-fragment order, split hi/lo bf16.
// Element Wt[k][n]: s=k>>5, lane=((k&31)>>3)<<4 | (n&15), e=k&7, f=n>>4
// -> idx = ((s*4+f)*64+lane)*8+e
__global__ void pack_kernel(const float* __restrict__ W,
                            unsigned short* __restrict__ Bhi,
                            unsigned short* __restrict__ Blo,
                            int* __restrict__ hist) {
    int tid = blockIdx.x * blockDim.x + threadIdx.x;   // 0 .. DIM*NEXP-1
    if (blockIdx.x == 0 && threadIdx.x <= NEXP) hist[threadIdx.x] = 0;  // hist + flag_cnt
    int n = tid >> 12;            // expert
    int k = tid & (DIM - 1);
    float w = W[tid];
    unsigned u = __float_as_uint(w);
    unsigned hr = bf16_hi_bits(u);
    float lo = w - __uint_as_float(hr);
    unsigned lr = bf16_hi_bits(__float_as_uint(lo));
    int s = k >> 5, kr = k & 31;
    int lane = ((kr >> 3) << 4) | (n & 15);
    int e = kr & 7, f = n >> 4;
    size_t idx = ((((size_t)s * 4 + f) * 64 + lane) << 3) + e;
    Bhi[idx] = (unsigned short)(hr >> 16);
    Blo[idx] = (unsigned short)(lr >> 16);
}

// ---- router: 1024 blocks x 256 thr (4 waves = 4 K-quarters); 16 tokens/block
#define LOADAB(S, A0, A1, H0,H1,H2,H3, L0,L1,L2,L3) {            \
    A0 = *(const float4*)(xrow + (size_t)(S) * 32);              \
    A1 = *(const float4*)(xrow + (size_t)(S) * 32 + 4);          \
    const int bb_ = (S) * 256 + lane;                            \
    H0 = Bh4[bb_];       H1 = Bh4[bb_ + 64];                     \
    H2 = Bh4[bb_ + 128]; H3 = Bh4[bb_ + 192];                    \
    L0 = Bl4[bb_];       L1 = Bl4[bb_ + 64];                     \
    L2 = Bl4[bb_ + 128]; L3 = Bl4[bb_ + 192]; }

#define COMPUTE(A0, A1, H0,H1,H2,H3, L0,L1,L2,L3) {              \
    float fe[8] = {A0.x,A0.y,A0.z,A0.w,A1.x,A1.y,A1.z,A1.w};     \
    short he[8], le[8];                                          \
    _Pragma("unroll")                                            \
    for (int e_ = 0; e_ < 8; ++e_) {                             \
        unsigned u_ = __float_as_uint(fe[e_]);                   \
        unsigned hr_ = bf16_hi_bits(u_);                         \
        he[e_] = (short)(hr_ >> 16);                             \
        float lo_ = fe[e_] - __uint_as_float(hr_);               \
        le[e_] = (short)(bf16_hi_bits(__float_as_uint(lo_)) >> 16); } \
    bf16x8 ah = {he[0],he[1],he[2],he[3],he[4],he[5],he[6],he[7]};    \
    bf16x8 al = {le[0],le[1],le[2],le[3],le[4],le[5],le[6],le[7]};    \
    bf16x8 b_;                                                   \
    b_ = __builtin_bit_cast(bf16x8, H0);                         \
    acc0 = __builtin_amdgcn_mfma_f32_16x16x32_bf16(ah, b_, acc0, 0,0,0); \
    acc0 = __builtin_amdgcn_mfma_f32_16x16x32_bf16(al, b_, acc0, 0,0,0); \
    b_ = __builtin_bit_cast(bf16x8, L0);                         \
    acc0 = __builtin_amdgcn_mfma_f32_16x16x32_bf16(ah, b_, acc0, 0,0,0); \
    b_ = __builtin_bit_cast(bf16x8, H1);                         \
    acc1 = __builtin_amdgcn_mfma_f32_16x16x32_bf16(ah, b_, acc1, 0,0,0); \
    acc1 = __builtin_amdgcn_mfma_f32_16x16x32_bf16(al, b_, acc1, 0,0,0); \
    b_ = __builtin_bit_cast(bf16x8, L1);                         \
    acc1 = __builtin_amdgcn_mfma_f32_16x16x32_bf16(ah, b_, acc1, 0,0,0); \
    b_ = __builtin_bit_cast(bf16x8, H2);                         \
    acc2 = __builtin_amdgcn_mfma_f32_16x16x32_bf16(ah, b_, acc2, 0,0,0); \
    acc2 = __builtin_amdgcn_mfma_f32_16x16x32_bf16(al, b_, acc2, 0,0,0); \
    b_ = __builtin_bit_cast(bf16x8, L2);                         \
    acc2 = __builtin_amdgcn_mfma_f32_16x16x32_bf16(ah, b_, acc2, 0,0,0); \
    b_ = __builtin_bit_cast(bf16x8, H3);                         \
    acc3 = __builtin_amdgcn_mfma_f32_16x16x32_bf16(ah, b_, acc3, 0,0,0); \
    acc3 = __builtin_amdgcn_mfma_f32_16x16x32_bf16(al, b_, acc3, 0,0,0); \
    b_ = __builtin_bit_cast(bf16x8, L3);                         \
    acc3 = __builtin_amdgcn_mfma_f32_16x16x32_bf16(ah, b_, acc3, 0,0,0); }

__global__ __launch_bounds__(256, 4) void router_kernel(
    const float* __restrict__ x,
    const float* __restrict__ b,
    const float* __restrict__ bi,
    const float* __restrict__ rand_u,
    const uint4* __restrict__ Bh4,
    const uint4* __restrict__ Bl4,
    float* __restrict__ out,          // probs | indices-as-float | bi_new
    int* __restrict__ hist_g) {       // hist[64] | flag_cnt | flag_list
    __shared__ float part[KSPLIT][16][NEXP];   // 16KB K-partials
    __shared__ int lds_hist[NEXP];

    const int lane = threadIdx.x & 63;
    const int wave = __builtin_amdgcn_readfirstlane(threadIdx.x >> 6);  // K-quarter
    if (threadIdx.x < NEXP) lds_hist[threadIdx.x] = 0;

    const int t0 = blockIdx.x * 16;
    const int row_a = lane & 15;           // A row (token) / C col (expert) role
    const int kg = lane >> 4;              // A k-group / C row-group
    const float* xrow = x + (size_t)(t0 + row_a) * DIM + kg * 8;
    const int Sb = wave * STEPS;           // this wave's K-step base

    f32x4 acc0 = {0,0,0,0}, acc1 = {0,0,0,0}, acc2 = {0,0,0,0}, acc3 = {0,0,0,0};

    float4 a0A, a1A, a0B, a1B;
    uint4 h0A,h1A,h2A,h3A, l0A,l1A,l2A,l3A;
    uint4 h0B,h1B,h2B,h3B, l0B,l1B,l2B,l3B;

    LOADAB(Sb, a0A,a1A, h0A,h1A,h2A,h3A, l0A,l1A,l2A,l3A);
    for (int s = 0; s < STEPS; s += 2) {
        LOADAB(Sb + s + 1, a0B,a1B, h0B,h1B,h2B,h3B, l0B,l1B,l2B,l3B);
        COMPUTE(a0A,a1A, h0A,h1A,h2A,h3A, l0A,l1A,l2A,l3A);
        if (s + 2 < STEPS)
            LOADAB(Sb + s + 2, a0A,a1A, h0A,h1A,h2A,h3A, l0A,l1A,l2A,l3A);
        COMPUTE(a0B,a1B, h0B,h1B,h2B,h3B, l0B,l1B,l2B,l3B);
    }

    // write this wave's K-partial: C layout col=lane&15 (expert), row=kg*4+r (token)
#pragma unroll
    for (int r = 0; r < 4; ++r) {
        const int tr = kg * 4 + r;
        part[wave][tr][ 0 + row_a] = acc0[r];
        part[wave][tr][16 + row_a] = acc1[r];
        part[wave][tr][32 + row_a] = acc2[r];
        part[wave][tr][48 + row_a] = acc3[r];
    }
    __syncthreads();

    const float b_lane  = b[lane];
    const float bi_lane = bi[lane];
    int* flag_cnt  = hist_g + NEXP;
    int* flag_list = hist_g + NEXP + 1;

    for (int t = wave * 4; t < wave * 4 + 4; ++t) {
        const float vub = ((part[0][t][lane] + part[1][t][lane]) +
                           (part[2][t][lane] + part[3][t][lane])) + b_lane;
        float cur_l = vub + bi_lane;

        float selv  = -INFINITY;
        int   selidx = 0;
#pragma unroll
        for (int j = 0; j <= TOPK; ++j) {       // top-9: gap-check 8/9 boundary too
            float bv = cur_l;
            int   bidx = lane;
#pragma unroll
            for (int s = 1; s < 64; s <<= 1) {
                float ov = __shfl_xor(bv, s, 64);
                int   oi = __shfl_xor(bidx, s, 64);
                bool take = (ov > bv) || (ov == bv && oi < bidx);
                if (take) { bv = ov; bidx = oi; }
            }
            if (lane == j) { selv = bv; selidx = bidx; }
            if (lane == bidx) cur_l = -INFINITY;
        }

        const int tt = t0 + t;
        float nxtv = __shfl_down(selv, 1, 64);
        bool  bad  = (lane < TOPK) && (selv - nxtv < EPS_GAP);
        if (__any(bad)) {
            if (lane == 0) {
                int p = atomicAdd(flag_cnt, 1);
                if (p < TOKENS) flag_list[p] = tt;
            }
        } else {
            float out_logit = __shfl(vub, selidx, 64);
            float sv = (lane < TOPK) ? out_logit : -INFINITY;
            float m = sv;
            m = fmaxf(m, __shfl_xor(m, 1, 64));
            m = fmaxf(m, __shfl_xor(m, 2, 64));
            m = fmaxf(m, __shfl_xor(m, 4, 64));
            float e = (lane < TOPK) ? expf(sv - m) : 0.f;
            float ssum = e;
            ssum += __shfl_xor(ssum, 1, 64);
            ssum += __shfl_xor(ssum, 2, 64);
            ssum += __shfl_xor(ssum, 4, 64);
            if (lane < TOPK) {
                float p = e / ssum;
                float r = rand_u[tt * TOPK + lane];
                out[tt * TOPK + lane] = (r > FILTER_R) ? p : 0.f;
                out[TOKENS * TOPK + tt * TOPK + lane] = (float)selidx;
                atomicAdd(&lds_hist[selidx], 1);
            }
        }
    }

    __syncthreads();
    if (threadIdx.x < NEXP) atomicAdd(&hist_g[threadIdx.x], lds_hist[threadIdx.x]);
}

// exact f64 redo: one block per flagged token, 4 waves split K
__global__ __launch_bounds__(256) void fallback_kernel(
    const float* __restrict__ x,
    const float* __restrict__ W,
    const float* __restrict__ b,
    const float* __restrict__ bi,
    const float* __restrict__ rand_u,
    float* __restrict__ out,
    int* __restrict__ hist_g) {
    __shared__ double part[4][64];
    const int lane = threadIdx.x & 63;
    const int wave = threadIdx.x >> 6;
    const int* flag_cnt  = hist_g + NEXP;
    const int* flag_list = hist_g + NEXP + 1;
    int n = *flag_cnt; if (n > TOKENS) n = TOKENS;

    for (int i = blockIdx.x; i < n; i += gridDim.x) {
        const int tt = flag_list[i];
        const float4* xr = (const float4*)(x + (size_t)tt * DIM);
        const float4* wr = (const float4*)(W + (size_t)lane * DIM);
        double d0 = 0.0, d1 = 0.0;
#pragma unroll 4
        for (int k4 = wave * 256; k4 < (wave + 1) * 256; ++k4) {
            float4 xv = xr[k4];
            float4 wv = wr[k4];
            d0 = fma((double)xv.x, (double)wv.x, d0);
            d1 = fma((double)xv.y, (double)wv.y, d1);
            d0 = fma((double)xv.z, (double)wv.z, d0);
            d1 = fma((double)xv.w, (double)wv.w, d1);
        }
        part[wave][lane] = d0 + d1;
        __syncthreads();
        if (wave == 0) {
            const double dvub = ((part[0][lane] + part[1][lane]) +
                                 (part[2][lane] + part[3][lane])) + (double)b[lane];
            double dcur = dvub + (double)bi[lane];
            float out_logit = -INFINITY;
            int   out_idx   = 0;
#pragma unroll
            for (int j = 0; j < TOPK; ++j) {
                double bv = dcur;
                int    bidx = lane;
#pragma unroll
                for (int s = 1; s < 64; s <<= 1) {
                    double ov = __shfl_xor(bv, s, 64);
                    int    oi = __shfl_xor(bidx, s, 64);
                    bool take = (ov > bv) || (ov == bv && oi < bidx);
                    if (take) { bv = ov; bidx = oi; }
                }
                float wub = (float)__shfl(dvub, bidx, 64);
                if (lane == j) { out_logit = wub; out_idx = bidx; }
                if (lane == bidx) dcur = -(double)INFINITY;
            }
            float sv = (lane < TOPK) ? out_logit : -INFINITY;
            float m = sv;
            m = fmaxf(m, __shfl_xor(m, 1, 64));
            m = fmaxf(m, __shfl_xor(m, 2, 64));
            m = fmaxf(m, __shfl_xor(m, 4, 64));
            float e = (lane < TOPK) ? expf(sv - m) : 0.f;
            float ssum = e;
            ssum += __shfl_xor(ssum, 1, 64);
            ssum += __shfl_xor(ssum, 2, 64);
            ssum += __shfl_xor(ssum, 4, 64);
            if (lane < TOPK) {
                float p = e / ssum;
                float r = rand_u[tt * TOPK + lane];
                out[tt * TOPK + lane] = (r > FILTER_R) ? p : 0.f;
                out[TOKENS * TOPK + tt * TOPK + lane] = (float)out_idx;
                atomicAdd(&hist_g[out_idx], 1);
            }
        }
        __syncthreads();
    }
}

__global__ void bias_update_kernel(const float* __restrict__ bi,
                                   const int* __restrict__ hist,
                                   float* __restrict__ out_bi) {
    int e = threadIdx.x;
    float c_avg = (float)TOKENS / (float)NEXP;     // 256
    float e_i = c_avg - (float)hist[e];
    float s = (e_i > 0.f) ? 1.f : ((e_i < 0.f) ? -1.f : 0.f);
    out_bi[e] = bi[e] + LOAD_LR * s;
}

extern "C" void kernel_launch(void* const* d_in, const int* in_sizes, int n_in,
                              void* d_out, int out_size, void* d_ws, size_t ws_size,
                              hipStream_t stream) {
    const float* x      = (const float*)d_in[0];
    const float* W      = (const float*)d_in[1];
    const float* b      = (const float*)d_in[2];
    const float* bi     = (const float*)d_in[3];
    const float* rand_u = (const float*)d_in[4];

    float* out = (float*)d_out;
    unsigned short* Bhi = (unsigned short*)d_ws;
    unsigned short* Blo = Bhi + BFRAG_ELEMS;
    int* hist = (int*)(Blo + BFRAG_ELEMS);

    // 1) split W into bf16 hi/lo, packed in MFMA B-fragment order; zero hist+flag
    pack_kernel<<<(DIM * NEXP) / 256, 256, 0, stream>>>(W, Bhi, Blo, hist);

    // 2) bf16x3 MFMA logits (K-split 4 waves) + top-k + softmax; ties -> flag list
    router_kernel<<<TOKENS / 16, 256, 0, stream>>>(
        x, b, bi, rand_u, (const uint4*)Bhi, (const uint4*)Blo, out, hist);

    // 3) exact f64 redo for flagged tokens (1 block each, 4-wave K-split)
    fallback_kernel<<<256, 256, 0, stream>>>(x, W, b, bi, rand_u, out, hist);

    // 4) load-balance bias update -> out[262144..262208)
    bias_update_kernel<<<1, NEXP, 0, stream>>>(bi, hist, out + 2 * TOKENS * TOPK);
}

// Round 10
// 144.269 us; speedup vs baseline: 2.3625x; 1.0112x over previous
//
#include <hip/hip_runtime.h>
#include <hip/hip_bf16.h>
#include <math.h>

#define TOKENS 16384
#define DIM 4096
#define NEXP 64
#define TOPK 8
#define FILTER_R 0.62f
#define LOAD_LR 0.001f
#define EPS_GAP 1e-4f      // bf16x3 logit err ~1e-6 RMS; 100x margin

typedef __attribute__((ext_vector_type(8))) short bf16x8;   // 8 bf16 in 4 VGPRs
typedef __attribute__((ext_vector_type(4))) float f32x4;

#define NSTEP 128                      // K-steps of 32
#define KSPLIT 8                       // waves per block, each owns 16 steps
#define STEPS (NSTEP / KSPLIT)         // 16
#define TPB 32                         // tokens per block (2 M-tiles share B regs)
#define BFRAG_ELEMS (NSTEP * 4 * 64 * 8)   // 262144 ushorts = 512KB per array

// ws: Bhi[512KB] | Blo[512KB] | hist[64] | flag_cnt | done_cnt | flag_list[16384]

__device__ __forceinline__ unsigned bf16_hi_bits(unsigned u) {
    // RTNE bf16, result as fp32 bit pattern (low 16 cleared)
    return (u + 0x7fffu + ((u >> 16) & 1u)) & 0xffff0000u;
}

// Coalesced pack: thread tid = ((s*4+f)*64+lane) produces the 8 consecutive-k
// elements (e=0..7) of one B-fragment slot: n = f*16+(lane&15),
// k = s*32+(lane>>4)*8+e  ->  32B contiguous read, 16B contiguous store. Same
// index mapping as R8/R9 (verified bijection), just coalesced.
__global__ void pack_kernel(const float* __restrict__ W,
                            uint4* __restrict__ Bhi,
                            uint4* __restrict__ Blo,
                            int* __restrict__ hist) {
    int tid = blockIdx.x * blockDim.x + threadIdx.x;     // 0 .. 32767
    if (blockIdx.x == 0 && threadIdx.x < NEXP + 2) hist[threadIdx.x] = 0; // hist|flag|done
    int s = tid >> 8, f = (tid >> 6) & 3, lane = tid & 63;
    int n = f * 16 + (lane & 15);
    int k0 = s * 32 + ((lane >> 4) << 3);
    const float* wp = W + (size_t)n * DIM + k0;
    float4 wa = *(const float4*)wp;
    float4 wb = *(const float4*)(wp + 4);
    float fe[8] = {wa.x, wa.y, wa.z, wa.w, wb.x, wb.y, wb.z, wb.w};
    unsigned hh[8], ll[8];
#pragma unroll
    for (int e = 0; e < 8; ++e) {
        unsigned u = __float_as_uint(fe[e]);
        unsigned hr = bf16_hi_bits(u);
        hh[e] = hr >> 16;
        float lo = fe[e] - __uint_as_float(hr);
        ll[e] = bf16_hi_bits(__float_as_uint(lo)) >> 16;
    }
    Bhi[tid] = make_uint4(hh[0] | (hh[1] << 16), hh[2] | (hh[3] << 16),
                          hh[4] | (hh[5] << 16), hh[6] | (hh[7] << 16));
    Blo[tid] = make_uint4(ll[0] | (ll[1] << 16), ll[2] | (ll[3] << 16),
                          ll[4] | (ll[5] << 16), ll[6] | (ll[7] << 16));
}

#define MF(A, B, C) C = __builtin_amdgcn_mfma_f32_16x16x32_bf16(A, B, C, 0, 0, 0)

#define SPLIT8(A0, A1, AH, AL) {                                      \
    float fe[8] = {A0.x,A0.y,A0.z,A0.w,A1.x,A1.y,A1.z,A1.w};          \
    short he[8], le[8];                                               \
    _Pragma("unroll")                                                 \
    for (int e_ = 0; e_ < 8; ++e_) {                                  \
        unsigned u_ = __float_as_uint(fe[e_]);                        \
        unsigned hr_ = bf16_hi_bits(u_);                              \
        he[e_] = (short)(hr_ >> 16);                                  \
        float lo_ = fe[e_] - __uint_as_float(hr_);                    \
        le[e_] = (short)(bf16_hi_bits(__float_as_uint(lo_)) >> 16); } \
    AH = (bf16x8){he[0],he[1],he[2],he[3],he[4],he[5],he[6],he[7]};   \
    AL = (bf16x8){le[0],le[1],le[2],le[3],le[4],le[5],le[6],le[7]}; }

#define LOADX(S, P0, P1, Q0, Q1) {                        \
    P0 = *(const float4*)(xrow0 + (size_t)(S) * 32);      \
    P1 = *(const float4*)(xrow0 + (size_t)(S) * 32 + 4);  \
    Q0 = *(const float4*)(xrow1 + (size_t)(S) * 32);      \
    Q1 = *(const float4*)(xrow1 + (size_t)(S) * 32 + 4); }

#define LOADB(S) { const int bb_ = (S) * 256 + lane;                 \
    h0 = Bh4[bb_];       h1 = Bh4[bb_ + 64];                         \
    h2 = Bh4[bb_ + 128]; h3 = Bh4[bb_ + 192];                        \
    l0 = Bl4[bb_];       l1 = Bl4[bb_ + 64];                         \
    l2 = Bl4[bb_ + 128]; l3 = Bl4[bb_ + 192]; }

// both M-tiles (P=tokens 0-15, Q=tokens 16-31) consume the SAME B registers
#define COMPUTE2(P0, P1, Q0, Q1) {                                       \
    bf16x8 pah, pal, qah, qal, b_;                                       \
    SPLIT8(P0, P1, pah, pal); SPLIT8(Q0, Q1, qah, qal);                  \
    b_ = __builtin_bit_cast(bf16x8, h0);                                 \
    MF(pah,b_,acc0); MF(pal,b_,acc0); MF(qah,b_,acc4); MF(qal,b_,acc4);  \
    b_ = __builtin_bit_cast(bf16x8, l0);                                 \
    MF(pah,b_,acc0); MF(qah,b_,acc4);                                    \
    b_ = __builtin_bit_cast(bf16x8, h1);                                 \
    MF(pah,b_,acc1); MF(pal,b_,acc1); MF(qah,b_,acc5); MF(qal,b_,acc5);  \
    b_ = __builtin_bit_cast(bf16x8, l1);                                 \
    MF(pah,b_,acc1); MF(qah,b_,acc5);                                    \
    b_ = __builtin_bit_cast(bf16x8, h2);                                 \
    MF(pah,b_,acc2); MF(pal,b_,acc2); MF(qah,b_,acc6); MF(qal,b_,acc6);  \
    b_ = __builtin_bit_cast(bf16x8, l2);                                 \
    MF(pah,b_,acc2); MF(qah,b_,acc6);                                    \
    b_ = __builtin_bit_cast(bf16x8, h3);                                 \
    MF(pah,b_,acc3); MF(pal,b_,acc3); MF(qah,b_,acc7); MF(qal,b_,acc7);  \
    b_ = __builtin_bit_cast(bf16x8, l3);                                 \
    MF(pah,b_,acc3); MF(qah,b_,acc7); }

// 512 blocks x 512 thr (8 waves = 8 K-slices); 32 tokens/block
__global__ __launch_bounds__(512, 4) void router_kernel(
    const float* __restrict__ x,
    const float* __restrict__ b,
    const float* __restrict__ bi,
    const float* __restrict__ rand_u,
    const uint4* __restrict__ Bh4,
    const uint4* __restrict__ Bl4,
    float* __restrict__ out,          // probs | indices-as-float | bi_new
    int* __restrict__ hist_g) {       // hist[64] | flag_cnt | done_cnt | flag_list
    __shared__ float part[KSPLIT][TPB][NEXP + 1];   // +1 pad: conflict-free writes
    __shared__ int lds_hist[NEXP];

    const int lane = threadIdx.x & 63;
    const int wave = __builtin_amdgcn_readfirstlane(threadIdx.x >> 6);  // K-slice
    if (threadIdx.x < NEXP) lds_hist[threadIdx.x] = 0;

    const int t0 = blockIdx.x * TPB;
    const int row_a = lane & 15;           // token row within tile / expert col in C
    const int kg = lane >> 4;              // A k-subgroup / C row-group
    const float* xrow0 = x + (size_t)(t0 + row_a) * DIM + kg * 8;
    const float* xrow1 = xrow0 + (size_t)16 * DIM;
    const int Sb = wave * STEPS;

    f32x4 acc0 = {0,0,0,0}, acc1 = {0,0,0,0}, acc2 = {0,0,0,0}, acc3 = {0,0,0,0};
    f32x4 acc4 = {0,0,0,0}, acc5 = {0,0,0,0}, acc6 = {0,0,0,0}, acc7 = {0,0,0,0};

    float4 p0A, p1A, q0A, q1A, p0B, p1B, q0B, q1B;
    uint4 h0, h1, h2, h3, l0, l1, l2, l3;

    LOADX(Sb, p0A, p1A, q0A, q1A);
    for (int s = 0; s < STEPS; s += 2) {
        LOADX(Sb + s + 1, p0B, p1B, q0B, q1B);
        LOADB(Sb + s);
        COMPUTE2(p0A, p1A, q0A, q1A);
        if (s + 2 < STEPS) LOADX(Sb + s + 2, p0A, p1A, q0A, q1A);
        LOADB(Sb + s + 1);
        COMPUTE2(p0B, p1B, q0B, q1B);
    }

    // C layout: col = lane&15 (expert within f-group), row = kg*4+r (token)
#pragma unroll
    for (int r = 0; r < 4; ++r) {
        const int tr = kg * 4 + r;
        part[wave][tr][ 0 + row_a] = acc0[r];
        part[wave][tr][16 + row_a] = acc1[r];
        part[wave][tr][32 + row_a] = acc2[r];
        part[wave][tr][48 + row_a] = acc3[r];
        part[wave][16 + tr][ 0 + row_a] = acc4[r];
        part[wave][16 + tr][16 + row_a] = acc5[r];
        part[wave][16 + tr][32 + row_a] = acc6[r];
        part[wave][16 + tr][48 + row_a] = acc7[r];
    }
    __syncthreads();

    const float b_lane  = b[lane];
    const float bi_lane = bi[lane];
    int* flag_cnt  = hist_g + NEXP;
    int* flag_list = hist_g + NEXP + 2;

    for (int t = wave * 4; t < wave * 4 + 4; ++t) {
        const float vub = (((part[0][t][lane] + part[1][t][lane]) +
                            (part[2][t][lane] + part[3][t][lane])) +
                           ((part[4][t][lane] + part[5][t][lane]) +
                            (part[6][t][lane] + part[7][t][lane]))) + b_lane;
        float cur_l = vub + bi_lane;

        float selv  = -INFINITY;
        int   selidx = 0;
#pragma unroll
        for (int j = 0; j <= TOPK; ++j) {       // top-9: gap-check 8/9 boundary too
            float bv = cur_l;
            int   bidx = lane;
#pragma unroll
            for (int s = 1; s < 64; s <<= 1) {
                float ov = __shfl_xor(bv, s, 64);
                int   oi = __shfl_xor(bidx, s, 64);
                bool take = (ov > bv) || (ov == bv && oi < bidx);
                if (take) { bv = ov; bidx = oi; }
            }
            if (lane == j) { selv = bv; selidx = bidx; }
            if (lane == bidx) cur_l = -INFINITY;
        }

        const int tt = t0 + t;
        float nxtv = __shfl_down(selv, 1, 64);
        bool  bad  = (lane < TOPK) && (selv - nxtv < EPS_GAP);
        if (__any(bad)) {
            if (lane == 0) {
                int p = atomicAdd(flag_cnt, 1);
                if (p < TOKENS) flag_list[p] = tt;
            }
        } else {
            float out_logit = __shfl(vub, selidx, 64);
            float sv = (lane < TOPK) ? out_logit : -INFINITY;
            float m = sv;
            m = fmaxf(m, __shfl_xor(m, 1, 64));
            m = fmaxf(m, __shfl_xor(m, 2, 64));
            m = fmaxf(m, __shfl_xor(m, 4, 64));
            float e = (lane < TOPK) ? expf(sv - m) : 0.f;
            float ssum = e;
            ssum += __shfl_xor(ssum, 1, 64);
            ssum += __shfl_xor(ssum, 2, 64);
            ssum += __shfl_xor(ssum, 4, 64);
            if (lane < TOPK) {
                float p = e / ssum;
                float r = rand_u[tt * TOPK + lane];
                out[tt * TOPK + lane] = (r > FILTER_R) ? p : 0.f;
                out[TOKENS * TOPK + tt * TOPK + lane] = (float)selidx;
                atomicAdd(&lds_hist[selidx], 1);
            }
        }
    }

    __syncthreads();
    if (threadIdx.x < NEXP) atomicAdd(&hist_g[threadIdx.x], lds_hist[threadIdx.x]);
}

// exact f64 redo: one block per flagged token, 4 waves split K.
// Last block (device-wide ticket) also does the load-balance bias update.
__global__ __launch_bounds__(256) void fallback_kernel(
    const float* __restrict__ x,
    const float* __restrict__ W,
    const float* __restrict__ b,
    const float* __restrict__ bi,
    const float* __restrict__ rand_u,
    float* __restrict__ out,
    int* __restrict__ hist_g) {
    __shared__ double part[4][64];
    __shared__ int last_flag;
    const int lane = threadIdx.x & 63;
    const int wave = threadIdx.x >> 6;
    const int* flag_cnt  = hist_g + NEXP;
    int* done_cnt        = hist_g + NEXP + 1;
    const int* flag_list = hist_g + NEXP + 2;
    int n = *flag_cnt; if (n > TOKENS) n = TOKENS;

    for (int i = blockIdx.x; i < n; i += gridDim.x) {
        const int tt = flag_list[i];
        const float4* xr = (const float4*)(x + (size_t)tt * DIM);
        const float4* wr = (const float4*)(W + (size_t)lane * DIM);
        double d0 = 0.0, d1 = 0.0;
#pragma unroll 4
        for (int k4 = wave * 256; k4 < (wave + 1) * 256; ++k4) {
            float4 xv = xr[k4];
            float4 wv = wr[k4];
            d0 = fma((double)xv.x, (double)wv.x, d0);
            d1 = fma((double)xv.y, (double)wv.y, d1);
            d0 = fma((double)xv.z, (double)wv.z, d0);
            d1 = fma((double)xv.w, (double)wv.w, d1);
        }
        part[wave][lane] = d0 + d1;
        __syncthreads();
        if (wave == 0) {
            const double dvub = ((part[0][lane] + part[1][lane]) +
                                 (part[2][lane] + part[3][lane])) + (double)b[lane];
            double dcur = dvub + (double)bi[lane];
            float out_logit = -INFINITY;
            int   out_idx   = 0;
#pragma unroll
            for (int j = 0; j < TOPK; ++j) {
                double bv = dcur;
                int    bidx = lane;
#pragma unroll
                for (int s = 1; s < 64; s <<= 1) {
                    double ov = __shfl_xor(bv, s, 64);
                    int    oi = __shfl_xor(bidx, s, 64);
                    bool take = (ov > bv) || (ov == bv && oi < bidx);
                    if (take) { bv = ov; bidx = oi; }
                }
                float wub = (float)__shfl(dvub, bidx, 64);
                if (lane == j) { out_logit = wub; out_idx = bidx; }
                if (lane == bidx) dcur = -(double)INFINITY;
            }
            float sv = (lane < TOPK) ? out_logit : -INFINITY;
            float m = sv;
            m = fmaxf(m, __shfl_xor(m, 1, 64));
            m = fmaxf(m, __shfl_xor(m, 2, 64));
            m = fmaxf(m, __shfl_xor(m, 4, 64));
            float e = (lane < TOPK) ? expf(sv - m) : 0.f;
            float ssum = e;
            ssum += __shfl_xor(ssum, 1, 64);
            ssum += __shfl_xor(ssum, 2, 64);
            ssum += __shfl_xor(ssum, 4, 64);
            if (lane < TOPK) {
                float p = e / ssum;
                float r = rand_u[tt * TOPK + lane];
                out[tt * TOPK + lane] = (r > FILTER_R) ? p : 0.f;
                out[TOKENS * TOPK + tt * TOPK + lane] = (float)out_idx;
                atomicAdd(&hist_g[out_idx], 1);
            }
        }
        __syncthreads();
    }

    // fused bias update: last block to finish does it (hist complete by then)
    __threadfence();
    if (threadIdx.x == 0)
        last_flag = (atomicAdd(done_cnt, 1) == (int)gridDim.x - 1);
    __syncthreads();
    if (last_flag && threadIdx.x < NEXP) {
        int c = atomicAdd(&hist_g[threadIdx.x], 0);   // coherent read
        float e_i = (float)TOKENS / (float)NEXP - (float)c;
        float s = (e_i > 0.f) ? 1.f : ((e_i < 0.f) ? -1.f : 0.f);
        out[2 * TOKENS * TOPK + threadIdx.x] = bi[threadIdx.x] + LOAD_LR * s;
    }
}

extern "C" void kernel_launch(void* const* d_in, const int* in_sizes, int n_in,
                              void* d_out, int out_size, void* d_ws, size_t ws_size,
                              hipStream_t stream) {
    const float* x      = (const float*)d_in[0];
    const float* W      = (const float*)d_in[1];
    const float* b      = (const float*)d_in[2];
    const float* bi     = (const float*)d_in[3];
    const float* rand_u = (const float*)d_in[4];

    float* out = (float*)d_out;
    unsigned short* Bhi = (unsigned short*)d_ws;
    unsigned short* Blo = Bhi + BFRAG_ELEMS;
    int* hist = (int*)(Blo + BFRAG_ELEMS);

    // 1) coalesced pack of W into bf16 hi/lo MFMA B-fragments; zero hist/flags
    pack_kernel<<<(NSTEP * 4 * 64) / 256, 256, 0, stream>>>(
        W, (uint4*)Bhi, (uint4*)Blo, hist);

    // 2) bf16x3 MFMA logits (8-way K-split, 32 tokens/block sharing B regs)
    router_kernel<<<TOKENS / TPB, 512, 0, stream>>>(
        x, b, bi, rand_u, (const uint4*)Bhi, (const uint4*)Blo, out, hist);

    // 3) exact f64 redo for flagged tokens + fused bias update
    fallback_kernel<<<256, 256, 0, stream>>>(x, W, b, bi, rand_u, out, hist);
}